// Round 10
// baseline (104.656 us; speedup 1.0000x reference)
//
#include <hip/hip_runtime.h>
#include <hip/hip_bf16.h>

#define KT 576   // CIN*9, GEMM k-order k' = (p*3+q)*64 + c

typedef __attribute__((ext_vector_type(8))) short  short8;
typedef __attribute__((ext_vector_type(4))) float  f32x4;

#define VMCNT(n) asm volatile("s_waitcnt vmcnt(" #n ")" ::: "memory")
#define SB() __builtin_amdgcn_sched_barrier(0)

__device__ __forceinline__ unsigned short f2bf(float f) {
  union { float f; unsigned int u; } v; v.f = f;
  return (unsigned short)((v.u + 0x7FFFu + ((v.u >> 16) & 1u)) >> 16);  // RNE
}

// ---------------------------------------------------------------------------
// Pre-pass: xC2 bf16, layout [hp 34][wp 34][bb 8][cs 8][bl 16][cl 8].
// ---------------------------------------------------------------------------
__global__ __launch_bounds__(256) void xC2_kernel(const float* __restrict__ x,
                                                  unsigned short* __restrict__ xC2) {
  const int hp = blockIdx.x, bb = blockIdx.y, t = threadIdx.x;
  __shared__ unsigned short tile[32 * 1024];   // [w 32][cs 8][bl 16][cl 8]
  const bool interior = (hp >= 1 && hp <= 32);
  if (interior) {
#pragma unroll 4
    for (int i = 0; i < 32; ++i) {
      const int row = i * 32 + (t >> 3);       // = bl*64 + c
      const int bl = row >> 6, c = row & 63;
      const int k = t & 7;
      const float4 v = *(const float4*)(x + ((size_t)(bb * 16 + bl) * 64 + c) * 1024 +
                                        (hp - 1) * 32 + k * 4);
      const int base = (k * 4) * 1024 + (c >> 3) * 128 + bl * 8 + (c & 7);
      tile[base]        = f2bf(v.x);
      tile[base + 1024] = f2bf(v.y);
      tile[base + 2048] = f2bf(v.z);
      tile[base + 3072] = f2bf(v.w);
    }
  }
  __syncthreads();
  unsigned short* dst = xC2 + (size_t)hp * 278528 + (size_t)bb * 1024;
  const uint4 z = make_uint4(0u, 0u, 0u, 0u);
  for (int idx = t; idx < 34 * 128; idx += 256) {
    const int wp = idx >> 7, s = idx & 127;
    uint4 v = z;
    if (interior && wp >= 1 && wp <= 32) v = *(const uint4*)&tile[(wp - 1) * 1024 + s * 8];
    *(uint4*)(dst + (size_t)wp * 8192 + s * 8) = v;
  }
}

// ---------------------------------------------------------------------------
// Main: 1024 blocks = (h 32) x (wq 8) x (dquad 4); target 2 blocks/CU.
// Each block: 4 chained mini-GEMMs (w = wq*4+j), M=128b x N=16d x K=576.
// W(16 rows) double-buffered in LDS (k'-ordered, XOR-swizzled); W(j+1)'s 9
// loads issued at gemm-j start; A 3-deep; counted vmcnt; macro-expanded.
// ---------------------------------------------------------------------------
__global__ __launch_bounds__(256, 2) void lc_main(const float* __restrict__ Wt,
                                                  const float* __restrict__ bias,
                                                  const unsigned short* __restrict__ xC2,
                                                  float* __restrict__ out) {
  __shared__ unsigned short Wl[2][16 * KT];   // 2 x 18432 B
  __shared__ float blds[64];                  // [j 4][dl 16]

  const int bid = (int)blockIdx.x;
  const int swz = (bid & 7) * 128 + (bid >> 3);   // 128-block chunks per XCD
  const int quad = swz & 3, wq = (swz >> 2) & 7, h = swz >> 5;
  const int t = threadIdx.x, lane = t & 63, wv = t >> 6;
  const int l15 = lane & 15, lg = lane >> 4;

  if (t < 64)
    blds[t] = bias[(quad * 16 + (t & 15)) * 1024 + h * 32 + wq * 4 + (t >> 4)];

  const unsigned short* xA = xC2 + (size_t)wv * 2048 + lg * 128 + l15 * 8;
  const int x7 = l15 & 7;
  const int wrow = l15 * KT;

  f32x4 acc[4][2];
#pragma unroll
  for (int j = 0; j < 4; ++j)
#pragma unroll
    for (int bt = 0; bt < 2; ++bt) acc[j][bt] = (f32x4){0.f, 0.f, 0.f, 0.f};

  short8 As0[3][3], As1[3][3];   // A slots [(j*6+g)%3][s]
  float4 wreg[9];

#define ISSUE_W(jj)                                                           \
  {                                                                           \
    const float* ws = Wt + ((size_t)(h * 32 + wq * 4 + (jj)) * 64 +           \
                            quad * 16) * KT;                                  \
    _Pragma("unroll")                                                         \
    for (int i = 0; i < 9; ++i) {                                             \
      const float4* p = (const float4*)ws + (i * 256 + t);                    \
      asm volatile("global_load_dwordx4 %0, %1, off" : "=v"(wreg[i]) : "v"(p)); \
    }                                                                         \
  }

#define ISSUE_A(K)                                                            \
  {                                                                           \
    _Pragma("unroll")                                                         \
    for (int s = 0; s < 3; ++s) {                                             \
      const int step = ((K) % 6) * 3 + s;                                     \
      const int pq = step >> 1, p = pq / 3, q = pq - p * 3;                   \
      const size_t off = (size_t)(h + p) * 278528 +                           \
                         (size_t)(wq * 4 + (K) / 6 + q) * 8192 + (step & 1) * 512; \
      const short8* p0 = (const short8*)(xA + off);                           \
      const short8* p1 = (const short8*)(xA + off + 1024);                    \
      asm volatile("global_load_dwordx4 %0, %1, off" : "=v"(As0[(K) % 3][s]) : "v"(p0)); \
      asm volatile("global_load_dwordx4 %0, %1, off" : "=v"(As1[(K) % 3][s]) : "v"(p1)); \
    }                                                                         \
  }

#define SCATTER(buf)                                                          \
  {                                                                           \
    _Pragma("unroll")                                                         \
    for (int i = 0; i < 9; ++i) {                                             \
      const int f = (i * 256 + t) * 4;                                        \
      const int d = (((unsigned)(f >> 6)) * 7282u) >> 16;                     \
      int kn = f - d * 576;                                                   \
      int c = ((unsigned)kn * 7282u) >> 16;                                   \
      int r = kn - c * 9;                                                     \
      const float vv[4] = {wreg[i].x, wreg[i].y, wreg[i].z, wreg[i].w};       \
      _Pragma("unroll")                                                       \
      for (int jx = 0; jx < 4; ++jx) {                                        \
        const int kp = r * 64 + c;                                            \
        const int slot = (kp >> 3) ^ (d & 7);                                 \
        Wl[buf][d * KT + slot * 8 + (kp & 7)] = f2bf(vv[jx]);                 \
        if (++r == 9) { r = 0; ++c; }                                         \
      }                                                                       \
    }                                                                         \
  }

#define STEP(jj, gg, NN)                                                      \
  {                                                                           \
    VMCNT(NN);                                                                \
    SB();                                                                     \
    _Pragma("unroll")                                                         \
    for (int s = 0; s < 3; ++s) {                                             \
      const int sb = ((gg) * 3 + s) * 4 + lg;                                 \
      const short8 b0 = *(const short8*)&Wl[(jj) & 1][wrow + ((sb ^ x7) << 3)]; \
      acc[(jj)][0] = __builtin_amdgcn_mfma_f32_16x16x32_bf16(As0[((jj) * 6 + (gg)) % 3][s], b0, acc[(jj)][0], 0, 0, 0); \
      acc[(jj)][1] = __builtin_amdgcn_mfma_f32_16x16x32_bf16(As1[((jj) * 6 + (gg)) % 3][s], b0, acc[(jj)][1], 0, 0, 0); \
    }                                                                         \
  }

  // ---- prologue: W0 (9) + A(0..2) (18); drain W0, scatter buf0 ----
  ISSUE_W(0);
  ISSUE_A(0); ISSUE_A(1); ISSUE_A(2);
  VMCNT(18);
  SB();
  SCATTER(0);
  __syncthreads();

  // ---- j=0 ----
  ISSUE_W(1);
  STEP(0, 0, 21); ISSUE_A(3);
  STEP(0, 1, 21); ISSUE_A(4);
  STEP(0, 2, 21); ISSUE_A(5);
  STEP(0, 3, 12); ISSUE_A(6);    // vmcnt(12) also drains W1
  STEP(0, 4, 12); ISSUE_A(7);
  STEP(0, 5, 12); ISSUE_A(8);
  SCATTER(1);
  __syncthreads();

  // ---- j=1 ----
  ISSUE_W(2);
  STEP(1, 0, 21); ISSUE_A(9);
  STEP(1, 1, 21); ISSUE_A(10);
  STEP(1, 2, 21); ISSUE_A(11);
  STEP(1, 3, 12); ISSUE_A(12);
  STEP(1, 4, 12); ISSUE_A(13);
  STEP(1, 5, 12); ISSUE_A(14);
  SCATTER(0);
  __syncthreads();

  // ---- j=2 ----
  ISSUE_W(3);
  STEP(2, 0, 21); ISSUE_A(15);
  STEP(2, 1, 21); ISSUE_A(16);
  STEP(2, 2, 21); ISSUE_A(17);
  STEP(2, 3, 12); ISSUE_A(18);
  STEP(2, 4, 12); ISSUE_A(19);
  STEP(2, 5, 12); ISSUE_A(20);
  SCATTER(1);
  __syncthreads();

  // ---- j=3 (no W prefetch) ----
  STEP(3, 0, 12); ISSUE_A(21);
  STEP(3, 1, 12); ISSUE_A(22);
  STEP(3, 2, 12); ISSUE_A(23);
  STEP(3, 3, 12);
  STEP(3, 4, 6);
  STEP(3, 5, 0);

  // ---- epilogue: float4 over the 4 consecutive w ----
#pragma unroll
  for (int bt = 0; bt < 2; ++bt) {
#pragma unroll
    for (int i = 0; i < 4; ++i) {
      const int b = wv * 32 + bt * 16 + lg * 4 + i;
      const int dg = quad * 16 + l15;
      float4 v;
      v.x = acc[0][bt][i] + blds[l15];
      v.y = acc[1][bt][i] + blds[16 + l15];
      v.z = acc[2][bt][i] + blds[32 + l15];
      v.w = acc[3][bt][i] + blds[48 + l15];
      *(float4*)(out + (size_t)b * 65536 + (size_t)dg * 1024 + h * 32 + wq * 4) = v;
    }
  }
}

extern "C" void kernel_launch(void* const* d_in, const int* in_sizes, int n_in,
                              void* d_out, int out_size, void* d_ws, size_t ws_size,
                              hipStream_t stream) {
  const float* x    = (const float*)d_in[0];
  const float* wt   = (const float*)d_in[1];
  const float* bias = (const float*)d_in[2];
  float* out        = (float*)d_out;
  unsigned short* xC2 = (unsigned short*)d_ws;   // 18,939,904 B

  xC2_kernel<<<dim3(34, 8), 256, 0, stream>>>(x, xC2);
  lc_main<<<1024, 256, 0, stream>>>(wt, bias, xC2, out);
}